// Round 17
// baseline (246.466 us; speedup 1.0000x reference)
//
#include <hip/hip_runtime.h>
#include <hip/hip_bf16.h>

// Problem constants
constexpr int   DIMC  = 512;
constexpr int   PARTC = 6;
constexpr int   NTOK  = 162;
constexpr float SCALING = 22.62741699796952f; // sqrt(512)
constexpr float LNEPS   = 1e-5f;

typedef __attribute__((ext_vector_type(8))) short bf16x8;
typedef __attribute__((ext_vector_type(4))) float f32x4;

// ---------------------------------------------------------------------------
// K0: transpose f32 [R][C] -> bf16 [C][R]
// ---------------------------------------------------------------------------
__global__ __launch_bounds__(256) void transpose_f32_bf16(
    const float* __restrict__ in, __hip_bfloat16* __restrict__ outp, int R, int C)
{
  __shared__ float tile[32][33];
  const int tx = threadIdx.x, ty = threadIdx.y;
  const int bx = blockIdx.x, by = blockIdx.y;
  const int c = bx * 32 + tx;
#pragma unroll
  for (int i = 0; i < 32; i += 8) {
    int r = by * 32 + ty + i;
    tile[ty + i][tx] = in[(size_t)r * C + c];
  }
  __syncthreads();
#pragma unroll
  for (int i = 0; i < 32; i += 8) {
    outp[(size_t)(bx * 32 + ty + i) * R + by * 32 + tx] =
        __float2bfloat16(tile[tx][ty + i]);
  }
}

// ---------------------------------------------------------------------------
// S2: SINGLE-PASS fused attention + /sqrt(512) + LayerNorm.  (R14 S1 with a
// 2-token unrolled hot loop for ILP — the only change, within-structure A/B.)
// x read from the memory system EXACTLY ONCE.  Block = one b, 256 thr.
// Lane owns dims [8l, 8l+8).  Wave processes tokens n = w, w+4, ... with
// fixed-max softmax (M=0); per iteration TWO tokens (n, n+4) with
// interleaved logit/shfl/exp/accumulate chains (12 indep shfl chains/level).
// 3 barriers total; ~25KB LDS.
// ---------------------------------------------------------------------------
__global__ __launch_bounds__(256, 3) void attn_ln_k(
    const float* __restrict__ x,     // [1024][162][512]
    const float* __restrict__ pt,    // [6][512]
    const float* __restrict__ g,     // [512]
    const float* __restrict__ bta,   // [512]
    __hip_bfloat16* __restrict__ outp)
{
  const int b = blockIdx.x;
  const int tid = threadIdx.x;
  const int w = tid >> 6;
  const int lane = tid & 63;
  const float* __restrict__ xb = x + (size_t)b * (NTOK * DIMC);

  __shared__ __align__(16) float ulds[2][PARTC][DIMC];  // 24 KB
  __shared__ float s_lw[4][PARTC];
  __shared__ float s_red[4][2 * PARTC];

  // pt slice for this lane: dims [8l, 8l+8)
  float4 pA[PARTC], pB[PARTC];
#pragma unroll
  for (int p = 0; p < PARTC; ++p) {
    pA[p] = *(const float4*)(pt + p * DIMC + 8 * lane);
    pB[p] = *(const float4*)(pt + p * DIMC + 8 * lane + 4);
  }

  float u[PARTC][8];
  float l[PARTC];
#pragma unroll
  for (int p = 0; p < PARTC; ++p) {
    l[p] = 0.f;
#pragma unroll
    for (int j = 0; j < 8; ++j) u[p][j] = 0.f;
  }

  // ---- single pass, 2-token unroll (no barriers) ----
  int n = w;
  for (; n + 4 < NTOK; n += 8) {
    const float* xr0 = xb + (size_t)n * DIMC + 8 * lane;
    const float* xr1 = xb + (size_t)(n + 4) * DIMC + 8 * lane;
    float4 xa0 = *(const float4*)xr0;
    float4 xc0 = *(const float4*)(xr0 + 4);
    float4 xa1 = *(const float4*)xr1;
    float4 xc1 = *(const float4*)(xr1 + 4);

    float a0[PARTC], a1[PARTC];
#pragma unroll
    for (int p = 0; p < PARTC; ++p) {
      a0[p] = xa0.x * pA[p].x + xa0.y * pA[p].y + xa0.z * pA[p].z + xa0.w * pA[p].w
            + xc0.x * pB[p].x + xc0.y * pB[p].y + xc0.z * pB[p].z + xc0.w * pB[p].w;
      a1[p] = xa1.x * pA[p].x + xa1.y * pA[p].y + xa1.z * pA[p].z + xa1.w * pA[p].w
            + xc1.x * pB[p].x + xc1.y * pB[p].y + xc1.z * pB[p].z + xc1.w * pB[p].w;
    }
#pragma unroll
    for (int off = 32; off > 0; off >>= 1) {
#pragma unroll
      for (int p = 0; p < PARTC; ++p) {
        a0[p] += __shfl_xor(a0[p], off);
        a1[p] += __shfl_xor(a1[p], off);
      }
    }
#pragma unroll
    for (int p = 0; p < PARTC; ++p) {
      const float w0 = __expf(a0[p]);   // fixed-max softmax (M=0)
      const float w1 = __expf(a1[p]);
      l[p] += w0 + w1;
      u[p][0] += w0 * xa0.x + w1 * xa1.x;
      u[p][1] += w0 * xa0.y + w1 * xa1.y;
      u[p][2] += w0 * xa0.z + w1 * xa1.z;
      u[p][3] += w0 * xa0.w + w1 * xa1.w;
      u[p][4] += w0 * xc0.x + w1 * xc1.x;
      u[p][5] += w0 * xc0.y + w1 * xc1.y;
      u[p][6] += w0 * xc0.z + w1 * xc1.z;
      u[p][7] += w0 * xc0.w + w1 * xc1.w;
    }
  }
  if (n < NTOK) {   // tail token
    const float* xr = xb + (size_t)n * DIMC + 8 * lane;
    float4 xa = *(const float4*)xr;
    float4 xc = *(const float4*)(xr + 4);
    float acc[PARTC];
#pragma unroll
    for (int p = 0; p < PARTC; ++p) {
      acc[p] = xa.x * pA[p].x + xa.y * pA[p].y + xa.z * pA[p].z + xa.w * pA[p].w
             + xc.x * pB[p].x + xc.y * pB[p].y + xc.z * pB[p].z + xc.w * pB[p].w;
    }
#pragma unroll
    for (int off = 32; off > 0; off >>= 1) {
#pragma unroll
      for (int p = 0; p < PARTC; ++p) acc[p] += __shfl_xor(acc[p], off);
    }
#pragma unroll
    for (int p = 0; p < PARTC; ++p) {
      const float we = __expf(acc[p]);
      l[p] += we;
      u[p][0] += we * xa.x; u[p][1] += we * xa.y;
      u[p][2] += we * xa.z; u[p][3] += we * xa.w;
      u[p][4] += we * xc.x; u[p][5] += we * xc.y;
      u[p][6] += we * xc.z; u[p][7] += we * xc.w;
    }
  }

  // ---- merge the 4 waves' partial (u, l) ----
  if (w >= 2) {
#pragma unroll
    for (int p = 0; p < PARTC; ++p) {
      *(float4*)&ulds[w - 2][p][8 * lane]     = make_float4(u[p][0], u[p][1], u[p][2], u[p][3]);
      *(float4*)&ulds[w - 2][p][8 * lane + 4] = make_float4(u[p][4], u[p][5], u[p][6], u[p][7]);
    }
    if (lane == 0) {
#pragma unroll
      for (int p = 0; p < PARTC; ++p) s_lw[w][p] = l[p];
    }
  }
  __syncthreads();
  if (w < 2) {
#pragma unroll
    for (int p = 0; p < PARTC; ++p) {
      float4 a = *(const float4*)&ulds[w][p][8 * lane];
      float4 c = *(const float4*)&ulds[w][p][8 * lane + 4];
      a.x += u[p][0]; a.y += u[p][1]; a.z += u[p][2]; a.w += u[p][3];
      c.x += u[p][4]; c.y += u[p][5]; c.z += u[p][6]; c.w += u[p][7];
      *(float4*)&ulds[w][p][8 * lane]     = a;
      *(float4*)&ulds[w][p][8 * lane + 4] = c;
    }
    if (lane == 0) {
#pragma unroll
      for (int p = 0; p < PARTC; ++p) s_lw[w][p] = l[p];
    }
  }
  __syncthreads();

  // ---- epilogue: thread owns dims (2t, 2t+1); y = u/(l*sqrt(512)); LN ----
  float lt[PARTC];
#pragma unroll
  for (int p = 0; p < PARTC; ++p)
    lt[p] = s_lw[0][p] + s_lw[1][p] + s_lw[2][p] + s_lw[3][p];

  float y0[PARTC], y1[PARTC], s1[PARTC], s2[PARTC];
#pragma unroll
  for (int p = 0; p < PARTC; ++p) {
    const float uu0 = ulds[0][p][2 * tid]     + ulds[1][p][2 * tid];
    const float uu1 = ulds[0][p][2 * tid + 1] + ulds[1][p][2 * tid + 1];
    const float inv = 1.f / (lt[p] * SCALING);
    y0[p] = uu0 * inv;
    y1[p] = uu1 * inv;
    s1[p] = y0[p] + y1[p];
    s2[p] = y0[p] * y0[p] + y1[p] * y1[p];
  }
#pragma unroll
  for (int off = 32; off > 0; off >>= 1) {
#pragma unroll
    for (int p = 0; p < PARTC; ++p) {
      s1[p] += __shfl_xor(s1[p], off);
      s2[p] += __shfl_xor(s2[p], off);
    }
  }
  if (lane == 0) {
#pragma unroll
    for (int p = 0; p < PARTC; ++p) {
      s_red[w][p] = s1[p];
      s_red[w][PARTC + p] = s2[p];
    }
  }
  __syncthreads();

  const float ga0 = g[2 * tid], ga1 = g[2 * tid + 1];
  const float bb0 = bta[2 * tid], bb1 = bta[2 * tid + 1];
  __hip_bfloat16* orow = outp + (size_t)b * PARTC * DIMC;
#pragma unroll
  for (int p = 0; p < PARTC; ++p) {
    float S = s_red[0][p] + s_red[1][p] + s_red[2][p] + s_red[3][p];
    float Q = s_red[0][PARTC + p] + s_red[1][PARTC + p] + s_red[2][PARTC + p] + s_red[3][PARTC + p];
    float mu = S * (1.f / 512.f);
    float var = Q * (1.f / 512.f) - mu * mu;
    float r = rsqrtf(var + LNEPS);
    __hip_bfloat162 hv;
    hv.x = __float2bfloat16((y0[p] - mu) * r * ga0 + bb0);
    hv.y = __float2bfloat16((y1[p] - mu) * r * ga1 + bb1);
    *(__hip_bfloat162*)(orow + p * DIMC + 2 * tid) = hv;
  }
}

// ---------------------------------------------------------------------------
// MFMA GEMM: C[M][N] = act(A[M][K] @ Bt[N][K]^T + bias)   (unchanged)
// ---------------------------------------------------------------------------
template <int BM, int BN, bool GELU>
__global__ __launch_bounds__(256) void gemm_bt(
    const __hip_bfloat16* __restrict__ A,
    const __hip_bfloat16* __restrict__ Bt,
    const float* __restrict__ bias,
    void* __restrict__ Cv,
    int M, int N, int K)
{
  constexpr int BK = 64;
  constexpr int LDT = BK + 16; // 80 bf16 = 160B row stride
  __shared__ __align__(16) unsigned short Al[BM][LDT];
  __shared__ __align__(16) unsigned short Bl[BN][LDT];

  const int tid = threadIdx.x;
  const int w = tid >> 6, lane = tid & 63;
  const int wr = w >> 1, wc = w & 1;
  const int tm = blockIdx.y * BM, tn = blockIdx.x * BN;
  constexpr int FM = BM / 32, FN = BN / 32;

  f32x4 acc[FM][FN];
#pragma unroll
  for (int m = 0; m < FM; ++m)
#pragma unroll
    for (int n = 0; n < FN; ++n) acc[m][n] = (f32x4){0.f, 0.f, 0.f, 0.f};

  const int srow = tid >> 3;        // 0..31
  const int scol = (tid & 7) * 8;   // element offset in K

  for (int k0 = 0; k0 < K; k0 += BK) {
    __syncthreads();
#pragma unroll
    for (int r = 0; r < BM / 32; ++r) {
      int row = r * 32 + srow;
      *(int4*)(&Al[row][scol]) =
          *(const int4*)(A + (size_t)(tm + row) * K + k0 + scol);
    }
#pragma unroll
    for (int r = 0; r < BN / 32; ++r) {
      int row = r * 32 + srow;
      *(int4*)(&Bl[row][scol]) =
          *(const int4*)(Bt + (size_t)(tn + row) * K + k0 + scol);
    }
    __syncthreads();

#pragma unroll
    for (int kk = 0; kk < 2; ++kk) {
      const int ko = kk * 32 + (lane >> 4) * 8;
      bf16x8 af[FM], bfr[FN];
#pragma unroll
      for (int m = 0; m < FM; ++m)
        af[m] = *(const bf16x8*)(&Al[wr * (BM / 2) + m * 16 + (lane & 15)][ko]);
#pragma unroll
      for (int n = 0; n < FN; ++n)
        bfr[n] = *(const bf16x8*)(&Bl[wc * (BN / 2) + n * 16 + (lane & 15)][ko]);
#pragma unroll
      for (int m = 0; m < FM; ++m)
#pragma unroll
        for (int n = 0; n < FN; ++n)
          acc[m][n] = __builtin_amdgcn_mfma_f32_16x16x32_bf16(
              af[m], bfr[n], acc[m][n], 0, 0, 0);
    }
  }

  // Epilogue: C/D layout col = lane&15, row = (lane>>4)*4 + r  [m89-verified]
  const int cl = lane & 15, rg = (lane >> 4) * 4;
#pragma unroll
  for (int m = 0; m < FM; ++m) {
#pragma unroll
    for (int n = 0; n < FN; ++n) {
      int col = tn + wc * (BN / 2) + n * 16 + cl;
      float bv = bias[col];
#pragma unroll
      for (int r = 0; r < 4; ++r) {
        int row = tm + wr * (BM / 2) + m * 16 + rg + r;
        float v = acc[m][n][r] + bv;
        if (GELU) {
          v = 0.5f * v * (1.f + erff(v * 0.7071067811865476f));
          ((__hip_bfloat16*)Cv)[(size_t)row * N + col] = __float2bfloat16(v);
        } else {
          ((float*)Cv)[(size_t)row * N + col] = v;
        }
      }
    }
  }
}

// ---------------------------------------------------------------------------
extern "C" void kernel_launch(void* const* d_in, const int* in_sizes, int n_in,
                              void* d_out, int out_size, void* d_ws, size_t ws_size,
                              hipStream_t stream)
{
  const float* x   = (const float*)d_in[0];
  const float* pt  = (const float*)d_in[1];
  const float* g   = (const float*)d_in[2];
  const float* bta = (const float*)d_in[3];
  const float* W1  = (const float*)d_in[4];
  const float* b1  = (const float*)d_in[5];
  const float* W2  = (const float*)d_in[6];
  const float* b2  = (const float*)d_in[7];
  float* outp = (float*)d_out;

  char* ws = (char*)d_ws;
  __hip_bfloat16* W1T = (__hip_bfloat16*)(ws);                    // 2048x512  bf16 (2 MB)
  __hip_bfloat16* W2T = (__hip_bfloat16*)(ws + 2097152);          // 512x2048  bf16 (2 MB)
  __hip_bfloat16* LNO = (__hip_bfloat16*)(ws + 4194304);          // 6144x512  bf16 (6 MB)
  __hip_bfloat16* H   = (__hip_bfloat16*)(ws + 10485760);         // 6144x2048 bf16 (25 MB)

  // K0: W1 (512x2048) -> W1T (2048x512); W2 (2048x512) -> W2T (512x2048)
  transpose_f32_bf16<<<dim3(2048 / 32, 512 / 32), dim3(32, 8), 0, stream>>>(W1, W1T, 512, 2048);
  transpose_f32_bf16<<<dim3(512 / 32, 2048 / 32), dim3(32, 8), 0, stream>>>(W2, W2T, 2048, 512);

  // S2: single-pass fused attention + LN -> LNO (x read once, 2-token unroll)
  attn_ln_k<<<1024, 256, 0, stream>>>(x, pt, g, bta, LNO);

  // K2: h = gelu(LNO @ W1 + b1) -> H (bf16)
  gemm_bt<128, 128, true><<<dim3(2048 / 128, 6144 / 128), 256, 0, stream>>>(
      LNO, W1T, b1, (void*)H, 6144, 2048, 512);

  // K3: out = H @ W2 + b2 -> d_out (f32)
  gemm_bt<64, 64, false><<<dim3(512 / 64, 6144 / 64), 256, 0, stream>>>(
      H, W2T, b2, (void*)outp, 6144, 512, 2048);
}

// Round 18
// 188.847 us; speedup vs baseline: 1.3051x; 1.3051x over previous
//
#include <hip/hip_runtime.h>
#include <hip/hip_bf16.h>

// Problem constants
constexpr int   DIMC  = 512;
constexpr int   PARTC = 6;
constexpr int   NTOK  = 162;
constexpr float SCALING = 22.62741699796952f; // sqrt(512)
constexpr float LNEPS   = 1e-5f;

typedef __attribute__((ext_vector_type(8))) short bf16x8;
typedef __attribute__((ext_vector_type(4))) float f32x4;

// ---------------------------------------------------------------------------
// K0: transpose f32 [R][C] -> bf16 [C][R]
// ---------------------------------------------------------------------------
__global__ __launch_bounds__(256) void transpose_f32_bf16(
    const float* __restrict__ in, __hip_bfloat16* __restrict__ outp, int R, int C)
{
  __shared__ float tile[32][33];
  const int tx = threadIdx.x, ty = threadIdx.y;
  const int bx = blockIdx.x, by = blockIdx.y;
  const int c = bx * 32 + tx;
#pragma unroll
  for (int i = 0; i < 32; i += 8) {
    int r = by * 32 + ty + i;
    tile[ty + i][tx] = in[(size_t)r * C + c];
  }
  __syncthreads();
#pragma unroll
  for (int i = 0; i < 32; i += 8) {
    outp[(size_t)(bx * 32 + ty + i) * R + by * 32 + tx] =
        __float2bfloat16(tile[tx][ty + i]);
  }
}

// ---------------------------------------------------------------------------
// S1 (R14 verbatim — proven best at 208 µs total): SINGLE-PASS fused
// attention + /sqrt(512) + LayerNorm.  x read EXACTLY ONCE.
// Block = one b, 256 thr.  Lane owns dims [8l, 8l+8).  Wave processes tokens
// n = w, w+4, ... with fixed-max softmax (M=0); 48-reg accumulator per lane.
// 3 barriers total; ~25KB LDS.
// ---------------------------------------------------------------------------
__global__ __launch_bounds__(256, 3) void attn_ln_k(
    const float* __restrict__ x,     // [1024][162][512]
    const float* __restrict__ pt,    // [6][512]
    const float* __restrict__ g,     // [512]
    const float* __restrict__ bta,   // [512]
    __hip_bfloat16* __restrict__ outp)
{
  const int b = blockIdx.x;
  const int tid = threadIdx.x;
  const int w = tid >> 6;
  const int lane = tid & 63;
  const float* __restrict__ xb = x + (size_t)b * (NTOK * DIMC);

  __shared__ __align__(16) float ulds[2][PARTC][DIMC];  // 24 KB
  __shared__ float s_lw[4][PARTC];
  __shared__ float s_red[4][2 * PARTC];

  // pt slice for this lane: dims [8l, 8l+8)
  float4 pA[PARTC], pB[PARTC];
#pragma unroll
  for (int p = 0; p < PARTC; ++p) {
    pA[p] = *(const float4*)(pt + p * DIMC + 8 * lane);
    pB[p] = *(const float4*)(pt + p * DIMC + 8 * lane + 4);
  }

  float u[PARTC][8];
  float l[PARTC];
#pragma unroll
  for (int p = 0; p < PARTC; ++p) {
    l[p] = 0.f;
#pragma unroll
    for (int j = 0; j < 8; ++j) u[p][j] = 0.f;
  }

  // ---- single pass: logits + online PV accumulate (no barriers) ----
  for (int n = w; n < NTOK; n += 4) {
    const float* xr = xb + (size_t)n * DIMC + 8 * lane;
    float4 xa = *(const float4*)xr;
    float4 xc = *(const float4*)(xr + 4);

    float acc[PARTC];
#pragma unroll
    for (int p = 0; p < PARTC; ++p) {
      acc[p] = xa.x * pA[p].x + xa.y * pA[p].y + xa.z * pA[p].z + xa.w * pA[p].w
             + xc.x * pB[p].x + xc.y * pB[p].y + xc.z * pB[p].z + xc.w * pB[p].w;
    }
#pragma unroll
    for (int off = 32; off > 0; off >>= 1) {
#pragma unroll
      for (int p = 0; p < PARTC; ++p) acc[p] += __shfl_xor(acc[p], off);
    }
#pragma unroll
    for (int p = 0; p < PARTC; ++p) {
      const float we = __expf(acc[p]);   // fixed-max softmax (M=0)
      l[p] += we;
      u[p][0] += we * xa.x; u[p][1] += we * xa.y;
      u[p][2] += we * xa.z; u[p][3] += we * xa.w;
      u[p][4] += we * xc.x; u[p][5] += we * xc.y;
      u[p][6] += we * xc.z; u[p][7] += we * xc.w;
    }
  }

  // ---- merge the 4 waves' partial (u, l) ----
  if (w >= 2) {
#pragma unroll
    for (int p = 0; p < PARTC; ++p) {
      *(float4*)&ulds[w - 2][p][8 * lane]     = make_float4(u[p][0], u[p][1], u[p][2], u[p][3]);
      *(float4*)&ulds[w - 2][p][8 * lane + 4] = make_float4(u[p][4], u[p][5], u[p][6], u[p][7]);
    }
    if (lane == 0) {
#pragma unroll
      for (int p = 0; p < PARTC; ++p) s_lw[w][p] = l[p];
    }
  }
  __syncthreads();
  if (w < 2) {
#pragma unroll
    for (int p = 0; p < PARTC; ++p) {
      float4 a = *(const float4*)&ulds[w][p][8 * lane];
      float4 c = *(const float4*)&ulds[w][p][8 * lane + 4];
      a.x += u[p][0]; a.y += u[p][1]; a.z += u[p][2]; a.w += u[p][3];
      c.x += u[p][4]; c.y += u[p][5]; c.z += u[p][6]; c.w += u[p][7];
      *(float4*)&ulds[w][p][8 * lane]     = a;
      *(float4*)&ulds[w][p][8 * lane + 4] = c;
    }
    if (lane == 0) {
#pragma unroll
      for (int p = 0; p < PARTC; ++p) s_lw[w][p] = l[p];
    }
  }
  __syncthreads();

  // ---- epilogue: thread owns dims (2t, 2t+1); y = u/(l*sqrt(512)); LN ----
  float lt[PARTC];
#pragma unroll
  for (int p = 0; p < PARTC; ++p)
    lt[p] = s_lw[0][p] + s_lw[1][p] + s_lw[2][p] + s_lw[3][p];

  float y0[PARTC], y1[PARTC], s1[PARTC], s2[PARTC];
#pragma unroll
  for (int p = 0; p < PARTC; ++p) {
    const float uu0 = ulds[0][p][2 * tid]     + ulds[1][p][2 * tid];
    const float uu1 = ulds[0][p][2 * tid + 1] + ulds[1][p][2 * tid + 1];
    const float inv = 1.f / (lt[p] * SCALING);
    y0[p] = uu0 * inv;
    y1[p] = uu1 * inv;
    s1[p] = y0[p] + y1[p];
    s2[p] = y0[p] * y0[p] + y1[p] * y1[p];
  }
#pragma unroll
  for (int off = 32; off > 0; off >>= 1) {
#pragma unroll
    for (int p = 0; p < PARTC; ++p) {
      s1[p] += __shfl_xor(s1[p], off);
      s2[p] += __shfl_xor(s2[p], off);
    }
  }
  if (lane == 0) {
#pragma unroll
    for (int p = 0; p < PARTC; ++p) {
      s_red[w][p] = s1[p];
      s_red[w][PARTC + p] = s2[p];
    }
  }
  __syncthreads();

  const float ga0 = g[2 * tid], ga1 = g[2 * tid + 1];
  const float bb0 = bta[2 * tid], bb1 = bta[2 * tid + 1];
  __hip_bfloat16* orow = outp + (size_t)b * PARTC * DIMC;
#pragma unroll
  for (int p = 0; p < PARTC; ++p) {
    float S = s_red[0][p] + s_red[1][p] + s_red[2][p] + s_red[3][p];
    float Q = s_red[0][PARTC + p] + s_red[1][PARTC + p] + s_red[2][PARTC + p] + s_red[3][PARTC + p];
    float mu = S * (1.f / 512.f);
    float var = Q * (1.f / 512.f) - mu * mu;
    float r = rsqrtf(var + LNEPS);
    __hip_bfloat162 hv;
    hv.x = __float2bfloat16((y0[p] - mu) * r * ga0 + bb0);
    hv.y = __float2bfloat16((y1[p] - mu) * r * ga1 + bb1);
    *(__hip_bfloat162*)(orow + p * DIMC + 2 * tid) = hv;
  }
}

// ---------------------------------------------------------------------------
// MFMA GEMM: C[M][N] = act(A[M][K] @ Bt[N][K]^T + bias)
// ---------------------------------------------------------------------------
template <int BM, int BN, bool GELU>
__global__ __launch_bounds__(256) void gemm_bt(
    const __hip_bfloat16* __restrict__ A,
    const __hip_bfloat16* __restrict__ Bt,
    const float* __restrict__ bias,
    void* __restrict__ Cv,
    int M, int N, int K)
{
  constexpr int BK = 64;
  constexpr int LDT = BK + 16; // 80 bf16 = 160B row stride
  __shared__ __align__(16) unsigned short Al[BM][LDT];
  __shared__ __align__(16) unsigned short Bl[BN][LDT];

  const int tid = threadIdx.x;
  const int w = tid >> 6, lane = tid & 63;
  const int wr = w >> 1, wc = w & 1;
  const int tm = blockIdx.y * BM, tn = blockIdx.x * BN;
  constexpr int FM = BM / 32, FN = BN / 32;

  f32x4 acc[FM][FN];
#pragma unroll
  for (int m = 0; m < FM; ++m)
#pragma unroll
    for (int n = 0; n < FN; ++n) acc[m][n] = (f32x4){0.f, 0.f, 0.f, 0.f};

  const int srow = tid >> 3;        // 0..31
  const int scol = (tid & 7) * 8;   // element offset in K

  for (int k0 = 0; k0 < K; k0 += BK) {
    __syncthreads();
#pragma unroll
    for (int r = 0; r < BM / 32; ++r) {
      int row = r * 32 + srow;
      *(int4*)(&Al[row][scol]) =
          *(const int4*)(A + (size_t)(tm + row) * K + k0 + scol);
    }
#pragma unroll
    for (int r = 0; r < BN / 32; ++r) {
      int row = r * 32 + srow;
      *(int4*)(&Bl[row][scol]) =
          *(const int4*)(Bt + (size_t)(tn + row) * K + k0 + scol);
    }
    __syncthreads();

#pragma unroll
    for (int kk = 0; kk < 2; ++kk) {
      const int ko = kk * 32 + (lane >> 4) * 8;
      bf16x8 af[FM], bfr[FN];
#pragma unroll
      for (int m = 0; m < FM; ++m)
        af[m] = *(const bf16x8*)(&Al[wr * (BM / 2) + m * 16 + (lane & 15)][ko]);
#pragma unroll
      for (int n = 0; n < FN; ++n)
        bfr[n] = *(const bf16x8*)(&Bl[wc * (BN / 2) + n * 16 + (lane & 15)][ko]);
#pragma unroll
      for (int m = 0; m < FM; ++m)
#pragma unroll
        for (int n = 0; n < FN; ++n)
          acc[m][n] = __builtin_amdgcn_mfma_f32_16x16x32_bf16(
              af[m], bfr[n], acc[m][n], 0, 0, 0);
    }
  }

  // Epilogue: C/D layout col = lane&15, row = (lane>>4)*4 + r  [m89-verified]
  const int cl = lane & 15, rg = (lane >> 4) * 4;
#pragma unroll
  for (int m = 0; m < FM; ++m) {
#pragma unroll
    for (int n = 0; n < FN; ++n) {
      int col = tn + wc * (BN / 2) + n * 16 + cl;
      float bv = bias[col];
#pragma unroll
      for (int r = 0; r < 4; ++r) {
        int row = tm + wr * (BM / 2) + m * 16 + rg + r;
        float v = acc[m][n][r] + bv;
        if (GELU) {
          v = 0.5f * v * (1.f + erff(v * 0.7071067811865476f));
          ((__hip_bfloat16*)Cv)[(size_t)row * N + col] = __float2bfloat16(v);
        } else {
          ((float*)Cv)[(size_t)row * N + col] = v;
        }
      }
    }
  }
}

// ---------------------------------------------------------------------------
extern "C" void kernel_launch(void* const* d_in, const int* in_sizes, int n_in,
                              void* d_out, int out_size, void* d_ws, size_t ws_size,
                              hipStream_t stream)
{
  const float* x   = (const float*)d_in[0];
  const float* pt  = (const float*)d_in[1];
  const float* g   = (const float*)d_in[2];
  const float* bta = (const float*)d_in[3];
  const float* W1  = (const float*)d_in[4];
  const float* b1  = (const float*)d_in[5];
  const float* W2  = (const float*)d_in[6];
  const float* b2  = (const float*)d_in[7];
  float* outp = (float*)d_out;

  char* ws = (char*)d_ws;
  __hip_bfloat16* W1T = (__hip_bfloat16*)(ws);                    // 2048x512  bf16 (2 MB)
  __hip_bfloat16* W2T = (__hip_bfloat16*)(ws + 2097152);          // 512x2048  bf16 (2 MB)
  __hip_bfloat16* LNO = (__hip_bfloat16*)(ws + 4194304);          // 6144x512  bf16 (6 MB)
  __hip_bfloat16* H   = (__hip_bfloat16*)(ws + 10485760);         // 6144x2048 bf16 (25 MB)

  // K0: W1 (512x2048) -> W1T (2048x512); W2 (2048x512) -> W2T (512x2048)
  transpose_f32_bf16<<<dim3(2048 / 32, 512 / 32), dim3(32, 8), 0, stream>>>(W1, W1T, 512, 2048);
  transpose_f32_bf16<<<dim3(512 / 32, 2048 / 32), dim3(32, 8), 0, stream>>>(W2, W2T, 2048, 512);

  // S1: single-pass fused attention + LN -> LNO (x read once; R14 verbatim)
  attn_ln_k<<<1024, 256, 0, stream>>>(x, pt, g, bta, LNO);

  // K2: h = gelu(LNO @ W1 + b1) -> H (bf16)
  gemm_bt<128, 128, true><<<dim3(2048 / 128, 6144 / 128), 256, 0, stream>>>(
      LNO, W1T, b1, (void*)H, 6144, 2048, 512);

  // K3: out = H @ W2 + b2 -> d_out (f32)  — BM=128 (was 64): 16 MFMAs/K-step
  gemm_bt<128, 64, false><<<dim3(512 / 64, 6144 / 128), 256, 0, stream>>>(
      H, W2T, b2, (void*)outp, 6144, 512, 2048);
}